// Round 11
// baseline (288.132 us; speedup 1.0000x reference)
//
#include <hip/hip_runtime.h>

#define B_SZ   4
#define N_SEQ  2048
#define DIM    1024
#define H_N    16
#define DH     64
#define INNER  1024
#define M_TOK  8192
// SCALE * log2(e): folded into Q in qkv_gemm epilogue so attn uses exp2 directly
#define QSCALE 0.1803368801111244f

typedef __attribute__((ext_vector_type(8))) short bf16x8;
typedef __attribute__((ext_vector_type(4))) float f32x4;
typedef __attribute__((ext_vector_type(4))) unsigned int u32x4;

__device__ __forceinline__ unsigned short f2b(float f) {
  union { float f; unsigned u; } v; v.f = f;
  unsigned r = v.u + 0x7fffu + ((v.u >> 16) & 1u);
  return (unsigned short)(r >> 16);
}

// async global->LDS, 16B per lane; LDS dest is wave-uniform base + lane*16
__device__ __forceinline__ void gl_lds16(const unsigned short* g, unsigned short* l) {
  __builtin_amdgcn_global_load_lds((const __attribute__((address_space(1))) void*)g,
                                   (__attribute__((address_space(3))) void*)l, 16, 0, 0);
}

// ---------------- x fp32 -> bf16 ----------------
__global__ __launch_bounds__(256) void cast_x(const float* __restrict__ x,
                                              unsigned short* __restrict__ xb) {
  int i = (blockIdx.x * 256 + threadIdx.x) * 4;
  float4 v = *(const float4*)(x + i);
  ushort4 o;
  o.x = f2b(v.x); o.y = f2b(v.y); o.z = f2b(v.z); o.w = f2b(v.w);
  *(ushort4*)(xb + i) = o;
}

// ---------------- W -> W^T bf16 (4 weights) ----------------
__global__ __launch_bounds__(256) void trans_w(const float* __restrict__ Wq,
    const float* __restrict__ Wk, const float* __restrict__ Wv,
    const float* __restrict__ Wo, unsigned short* __restrict__ WT) {
  const int z = blockIdx.z;
  const float* W = (z == 0) ? Wq : (z == 1) ? Wk : (z == 2) ? Wv : Wo;
  unsigned short* T = WT + (size_t)z * DIM * INNER;
  __shared__ float tile[64][65];
  const int n0 = blockIdx.x * 64, k0 = blockIdx.y * 64;
  const int tid = threadIdx.x;
#pragma unroll
  for (int it = 0; it < 16; it++) {
    int lin = it * 256 + tid;
    int r = lin >> 6, c = lin & 63;
    tile[r][c] = W[(size_t)(k0 + r) * 1024 + n0 + c];
  }
  __syncthreads();
#pragma unroll
  for (int it = 0; it < 16; it++) {
    int lin = it * 256 + tid;
    int r = lin >> 6, c = lin & 63;
    T[(size_t)(n0 + r) * 1024 + k0 + c] = f2b(tile[c][r]);
  }
}

// ---------------- QKV projection GEMM, round 16: gl_lds DOUBLE-BUFFER ------
// m97 loop had 2 barriers/K-step with the full global-load latency exposed at
// the vmcnt(0) drain before compute (MfmaUtil 26%, latency-bound at ~2
// blocks/CU). Now: LDS dbuf, ONE barrier/K-step; gl_lds for step kt+1 is
// issued right after the barrier and flies under step kt's 32 MFMAs, drained
// by the next barrier's vmcnt(0) (compiler-guaranteed before s_barrier).
// Disjoint buffers -> no read/write overlap; every reader of a buffer passes
// the next barrier before it is re-staged. No permlane anywhere (the only
// corruption mechanism this session). LDS 32->64 KB: 2 blocks/CU, matching
// the current register-limited residency. Accumulation order identical ->
// absmax stays bit-identical.
__global__ __launch_bounds__(256) void qkv_gemm(const unsigned short* __restrict__ xb,
    const unsigned short* __restrict__ WT, unsigned short* __restrict__ QKV) {
  __shared__ __align__(16) unsigned short As[2][2 * 128 * 32];
  __shared__ __align__(16) unsigned short Bs[2][2 * 128 * 32];
  const int tid = threadIdx.x;
  const int lane = tid & 63, wv = tid >> 6;
  const int quad = lane >> 4, l16 = lane & 15;
  const int wm = wv >> 1, wn = wv & 1;
  const int m0 = blockIdx.x * 128, n0 = blockIdx.y * 128;
  const unsigned short* Ag = xb + (size_t)m0 * DIM;
  const unsigned short* Bg = WT + (size_t)blockIdx.z * DIM * INNER + (size_t)n0 * DIM;
  unsigned short* Out = QKV + (size_t)blockIdx.z * M_TOK * INNER;

  f32x4 zero = {0.f, 0.f, 0.f, 0.f};
  f32x4 acc[4][4];
#pragma unroll
  for (int i = 0; i < 4; i++)
#pragma unroll
    for (int j = 0; j < 4; j++) acc[i][j] = zero;

  const int lr = lane >> 2, lc = (lane & 3) * 8;
  const int c0 = wv * 2, c1 = wv * 2 + 1;

  auto stage = [&](int k0, int bsel) {
#pragma unroll
    for (int h = 0; h < 2; h++) {
      gl_lds16(&Ag[(size_t)(c0 * 16 + lr) * DIM + k0 + h * 32 + lc], &As[bsel][h * 4096 + c0 * 512]);
      gl_lds16(&Ag[(size_t)(c1 * 16 + lr) * DIM + k0 + h * 32 + lc], &As[bsel][h * 4096 + c1 * 512]);
      gl_lds16(&Bg[(size_t)(c0 * 16 + lr) * DIM + k0 + h * 32 + lc], &Bs[bsel][h * 4096 + c0 * 512]);
      gl_lds16(&Bg[(size_t)(c1 * 16 + lr) * DIM + k0 + h * 32 + lc], &Bs[bsel][h * 4096 + c1 * 512]);
    }
  };

  stage(0, 0);
  const int NKT = DIM / 64;
  for (int kt = 0; kt < NKT; kt++) {
    __syncthreads();   // drains outstanding gl_lds (vmcnt 0) + joins waves
    if (kt + 1 < NKT) stage((kt + 1) * 64, (kt + 1) & 1);
    const unsigned short* as = As[kt & 1];
    const unsigned short* bs = Bs[kt & 1];
#pragma unroll
    for (int h = 0; h < 2; h++) {
      bf16x8 af[4], bfr[4];
#pragma unroll
      for (int i = 0; i < 4; i++)
        af[i] = *(const bf16x8*)&as[h * 4096 + (wm * 64 + i * 16 + l16) * 32 + quad * 8];
#pragma unroll
      for (int j = 0; j < 4; j++)
        bfr[j] = *(const bf16x8*)&bs[h * 4096 + (wn * 64 + j * 16 + l16) * 32 + quad * 8];
#pragma unroll
      for (int i = 0; i < 4; i++)
#pragma unroll
        for (int j = 0; j < 4; j++)
          acc[i][j] = __builtin_amdgcn_mfma_f32_16x16x32_bf16(af[i], bfr[j], acc[i][j], 0, 0, 0);
    }
  }
  if (blockIdx.z != 2) {
    const float cs = (blockIdx.z == 0) ? QSCALE : 1.0f;
#pragma unroll
    for (int i = 0; i < 4; i++) {
#pragma unroll
      for (int j = 0; j < 4; j++) {
        int n = n0 + wn * 64 + j * 16 + l16;
#pragma unroll
        for (int r = 0; r < 4; r++) {
          int m = m0 + wm * 64 + i * 16 + quad * 4 + r;
          Out[(size_t)m * INNER + n] = f2b(acc[i][j][r] * cs);
        }
      }
    }
  } else {
#pragma unroll
    for (int i = 0; i < 4; i++) {
#pragma unroll
      for (int j = 0; j < 4; j++) {
        int n = n0 + wn * 64 + j * 16 + l16;
        int h = n >> 6, dh = n & 63;
        int mbase = m0 + wm * 64 + i * 16 + quad * 4;
        int b = mbase >> 11, nq = mbase & 2047;
        unsigned lo = (unsigned)f2b(acc[i][j][0]) | ((unsigned)f2b(acc[i][j][1]) << 16);
        unsigned hi = (unsigned)f2b(acc[i][j][2]) | ((unsigned)f2b(acc[i][j][3]) << 16);
        uint2 pw; pw.x = lo; pw.y = hi;
        *(uint2*)&Out[((size_t)(b * H_N + h) * DH + dh) * N_SEQ + nq] = pw;
      }
    }
  }
}

// ---------------- flash attention (round-10 kernel, unchanged) -------------
#define KT 64
#define LSTR 72

__global__ __launch_bounds__(512, 4) void attn(const unsigned short* __restrict__ Q,
    const unsigned short* __restrict__ K, const unsigned short* __restrict__ VT,
    unsigned short* __restrict__ O) {
  __shared__ __align__(16) unsigned short Ks[2][KT * LSTR];
  __shared__ __align__(16) unsigned short VTs[2][DH * LSTR];
  const int tid = threadIdx.x;
  const int lane = tid & 63, w = tid >> 6;          // w in 0..7
  const int quad = lane >> 4, l16 = lane & 15;
  const int bh = blockIdx.y;
  const int b = bh >> 4, h = bh & 15;
  const int q0 = blockIdx.x * 256;                  // 256 q-rows per block
  const unsigned short* Qp = Q + ((size_t)b * N_SEQ) * INNER + h * DH;
  const unsigned short* Kp = K + ((size_t)b * N_SEQ) * INNER + h * DH;
  const unsigned short* VTp = VT + (size_t)bh * DH * N_SEQ;

  // Q fragments: this wave's 32 q-rows (2 x 16), B-operand layout
  bf16x8 aq[2][2];
#pragma unroll
  for (int qi = 0; qi < 2; qi++) {
    const unsigned short* qr = Qp + (size_t)(q0 + w * 32 + qi * 16 + l16) * INNER;
    aq[qi][0] = *(const bf16x8*)&qr[quad * 8];
    aq[qi][1] = *(const bf16x8*)&qr[32 + quad * 8];
  }

  bf16x8 vone;
#pragma unroll
  for (int j = 0; j < 8; j++) vone[j] = (short)0x3F80;

  f32x4 zero = {0.f, 0.f, 0.f, 0.f};
  f32x4 oacc[2][4];
  f32x4 lacc[2];
#pragma unroll
  for (int qi = 0; qi < 2; qi++) {
    lacc[qi] = zero;
#pragma unroll
    for (int t = 0; t < 4; t++) oacc[qi][t] = zero;
  }

  // staging lane map: 512 threads cover 64 rows x 64 shorts in one pass
  const int srow = tid >> 3, scol = (tid & 7) * 8;

  // prefetch tile 0 into registers
  uint4 kreg, vreg;
  kreg = *(const uint4*)&Kp[(size_t)srow * INNER + scol];
  vreg = *(const uint4*)&VTp[(size_t)srow * N_SEQ + scol];

  const int NT = N_SEQ / KT;
  for (int it = 0; it < NT; it++) {
    unsigned short* ks = Ks[it & 1];
    unsigned short* vs = VTs[it & 1];
    *(uint4*)&ks[srow * LSTR + scol] = kreg;
    *(uint4*)&vs[srow * LSTR + scol] = vreg;
    __syncthreads();   // stage writes drained; prior readers of this buffer done
    if (it + 1 < NT) {
      const int kn = (it + 1) * KT;
      kreg = *(const uint4*)&Kp[(size_t)(kn + srow) * INNER + scol];
      vreg = *(const uint4*)&VTp[(size_t)srow * N_SEQ + kn + scol];
    }

    // two key-halves of 32; per half: QK^T -> exp2 -> in-reg repack -> PV
#pragma unroll
    for (int half = 0; half < 2; half++) {
      f32x4 s[2][2];
#pragma unroll
      for (int t = 0; t < 2; t++)
#pragma unroll
        for (int qi = 0; qi < 2; qi++) s[t][qi] = zero;

#pragma unroll
      for (int kk = 0; kk < 2; kk++) {
#pragma unroll
        for (int t = 0; t < 2; t++) {
          bf16x8 ka = *(const bf16x8*)&ks[((half * 2 + t) * 16 + l16) * LSTR + kk * 32 + quad * 8];
#pragma unroll
          for (int qi = 0; qi < 2; qi++)
            s[t][qi] = __builtin_amdgcn_mfma_f32_16x16x32_bf16(ka, aq[qi][kk], s[t][qi], 0, 0, 0);
        }
      }

      bf16x8 pa[2];
#pragma unroll
      for (int qi = 0; qi < 2; qi++) {
#pragma unroll
        for (int t = 0; t < 2; t++)
#pragma unroll
          for (int r = 0; r < 4; r++)
            s[t][qi][r] = __builtin_amdgcn_exp2f(s[t][qi][r]);
        // C-layout (4 keys/lane) -> A-layout (8 keys/lane), in registers.
        // Fused asm with explicit s_nop wait-states: the CDNA VALU-write ->
        // v_permlane*-read hazard is NOT compiler-covered across asm borders
        // (this was the r2/r3/r5/r8 corruption; validated fix in r9).
        unsigned lo0, hi0, lo1, hi1;
        asm volatile(
            "v_cvt_pk_bf16_f32 %0, %4, %5\n\t"
            "v_cvt_pk_bf16_f32 %1, %6, %7\n\t"
            "v_cvt_pk_bf16_f32 %2, %8, %9\n\t"
            "v_cvt_pk_bf16_f32 %3, %10, %11\n\t"
            "s_nop 1\n\t"
            "v_permlane32_swap_b32 %0, %2\n\t"
            "v_permlane32_swap_b32 %1, %3\n\t"
            "s_nop 1\n\t"
            "v_permlane16_swap_b32 %0, %2\n\t"
            "v_permlane16_swap_b32 %1, %3\n\t"
            "s_nop 1"
            : "=&v"(lo0), "=&v"(hi0), "=&v"(lo1), "=&v"(hi1)
            : "v"(s[0][qi][0]), "v"(s[0][qi][1]), "v"(s[0][qi][2]), "v"(s[0][qi][3]),
              "v"(s[1][qi][0]), "v"(s[1][qi][1]), "v"(s[1][qi][2]), "v"(s[1][qi][3]));
        u32x4 pk;
        pk.x = lo0; pk.y = hi0; pk.z = lo1; pk.w = hi1;
        pa[qi] = __builtin_bit_cast(bf16x8, pk);
      }

      // PV + row-sum for this 32-key half
      lacc[0] = __builtin_amdgcn_mfma_f32_16x16x32_bf16(pa[0], vone, lacc[0], 0, 0, 0);
      lacc[1] = __builtin_amdgcn_mfma_f32_16x16x32_bf16(pa[1], vone, lacc[1], 0, 0, 0);
#pragma unroll
      for (int t2 = 0; t2 < 4; t2++) {
        bf16x8 vf = *(const bf16x8*)&vs[(t2 * 16 + l16) * LSTR + half * 32 + quad * 8];
        oacc[0][t2] = __builtin_amdgcn_mfma_f32_16x16x32_bf16(pa[0], vf, oacc[0][t2], 0, 0, 0);
        oacc[1][t2] = __builtin_amdgcn_mfma_f32_16x16x32_bf16(pa[1], vf, oacc[1][t2], 0, 0, 0);
      }
    }
  }

#pragma unroll
  for (int qi = 0; qi < 2; qi++) {
#pragma unroll
    for (int r = 0; r < 4; r++) {
      float rl = __builtin_amdgcn_rcpf(lacc[qi][r]);
      int qrow = q0 + w * 32 + qi * 16 + quad * 4 + r;
#pragma unroll
      for (int t2 = 0; t2 < 4; t2++) {
        int col = h * DH + t2 * 16 + l16;
        O[((size_t)b * N_SEQ + qrow) * INNER + col] = f2b(oacc[qi][t2][r] * rl);
      }
    }
  }
}

// ---------------- output GEMM, round 16: same gl_lds double-buffer ---------
__global__ __launch_bounds__(256) void out_gemm(const unsigned short* __restrict__ Ob,
    const unsigned short* __restrict__ WoT, const float* __restrict__ bo,
    float* __restrict__ out) {
  __shared__ __align__(16) unsigned short As[2][2 * 128 * 32];
  __shared__ __align__(16) unsigned short Bs[2][2 * 64 * 32];
  const int tid = threadIdx.x;
  const int lane = tid & 63, wv = tid >> 6;
  const int quad = lane >> 4, l16 = lane & 15;
  const int wm = wv >> 1, wn = wv & 1;
  const int m0 = blockIdx.x * 128, n0 = blockIdx.y * 64;
  const unsigned short* Ag = Ob + (size_t)m0 * INNER;
  const unsigned short* Bg = WoT + (size_t)n0 * INNER;

  f32x4 zero = {0.f, 0.f, 0.f, 0.f};
  f32x4 acc[4][2];
#pragma unroll
  for (int i = 0; i < 4; i++)
#pragma unroll
    for (int j = 0; j < 2; j++) acc[i][j] = zero;

  const int lr = lane >> 2, lc = (lane & 3) * 8;
  const int c0 = wv * 2, c1 = wv * 2 + 1;
  const int cb = wv;

  auto stage = [&](int k0, int bsel) {
#pragma unroll
    for (int h = 0; h < 2; h++) {
      gl_lds16(&Ag[(size_t)(c0 * 16 + lr) * INNER + k0 + h * 32 + lc], &As[bsel][h * 4096 + c0 * 512]);
      gl_lds16(&Ag[(size_t)(c1 * 16 + lr) * INNER + k0 + h * 32 + lc], &As[bsel][h * 4096 + c1 * 512]);
      gl_lds16(&Bg[(size_t)(cb * 16 + lr) * INNER + k0 + h * 32 + lc], &Bs[bsel][h * 2048 + cb * 512]);
    }
  };

  stage(0, 0);
  const int NKT = INNER / 64;
  for (int kt = 0; kt < NKT; kt++) {
    __syncthreads();   // drains outstanding gl_lds (vmcnt 0) + joins waves
    if (kt + 1 < NKT) stage((kt + 1) * 64, (kt + 1) & 1);
    const unsigned short* as = As[kt & 1];
    const unsigned short* bs = Bs[kt & 1];
#pragma unroll
    for (int h = 0; h < 2; h++) {
      bf16x8 af[4], bfr[2];
#pragma unroll
      for (int i = 0; i < 4; i++)
        af[i] = *(const bf16x8*)&as[h * 4096 + (wm * 64 + i * 16 + l16) * 32 + quad * 8];
#pragma unroll
      for (int j = 0; j < 2; j++)
        bfr[j] = *(const bf16x8*)&bs[h * 2048 + (wn * 32 + j * 16 + l16) * 32 + quad * 8];
#pragma unroll
      for (int i = 0; i < 4; i++)
#pragma unroll
        for (int j = 0; j < 2; j++)
          acc[i][j] = __builtin_amdgcn_mfma_f32_16x16x32_bf16(af[i], bfr[j], acc[i][j], 0, 0, 0);
    }
  }
#pragma unroll
  for (int i = 0; i < 4; i++) {
#pragma unroll
    for (int j = 0; j < 2; j++) {
      int n = n0 + wn * 32 + j * 16 + l16;
      float bias = bo[n];
#pragma unroll
      for (int r = 0; r < 4; r++) {
        int m = m0 + wm * 64 + i * 16 + quad * 4 + r;
        out[(size_t)m * DIM + n] = acc[i][j][r] + bias;
      }
    }
  }
}

extern "C" void kernel_launch(void* const* d_in, const int* in_sizes, int n_in,
                              void* d_out, int out_size, void* d_ws, size_t ws_size,
                              hipStream_t stream) {
  const float* x  = (const float*)d_in[0];
  const float* Wq = (const float*)d_in[1];
  const float* Wk = (const float*)d_in[2];
  const float* Wv = (const float*)d_in[3];
  const float* Wo = (const float*)d_in[4];
  const float* bo = (const float*)d_in[5];

  char* ws = (char*)d_ws;
  unsigned short* xb   = (unsigned short*)ws;                       // 16 MiB
  unsigned short* WT   = (unsigned short*)(ws + (size_t)16777216);  // 8 MiB
  unsigned short* QKV  = (unsigned short*)(ws + (size_t)25165824);  // 48 MiB: Q,K tok-major + V^T
  unsigned short* Obuf = (unsigned short*)(ws + (size_t)75497472);  // 16 MiB

  cast_x<<<dim3(8192), 256, 0, stream>>>(x, xb);
  trans_w<<<dim3(16, 16, 4), 256, 0, stream>>>(Wq, Wk, Wv, Wo, WT);
  qkv_gemm<<<dim3(64, 8, 3), 256, 0, stream>>>(xb, WT, QKV);
  attn<<<dim3(8, 64), 512, 0, stream>>>(QKV,
                                        QKV + (size_t)M_TOK * INNER,
                                        QKV + (size_t)2 * M_TOK * INNER,
                                        Obuf);
  out_gemm<<<dim3(64, 16), 256, 0, stream>>>(Obuf, WT + (size_t)3 * DIM * INNER, bo,
                                             (float*)d_out);
}

// Round 12
// 251.633 us; speedup vs baseline: 1.1450x; 1.1450x over previous
//
#include <hip/hip_runtime.h>

#define B_SZ   4
#define N_SEQ  2048
#define DIM    1024
#define H_N    16
#define DH     64
#define INNER  1024
#define M_TOK  8192
// SCALE * log2(e): folded into Q in qkv_gemm epilogue so attn uses exp2 directly
#define QSCALE 0.1803368801111244f

typedef __attribute__((ext_vector_type(8))) short bf16x8;
typedef __attribute__((ext_vector_type(4))) float f32x4;
typedef __attribute__((ext_vector_type(4))) unsigned int u32x4;

__device__ __forceinline__ unsigned short f2b(float f) {
  union { float f; unsigned u; } v; v.f = f;
  unsigned r = v.u + 0x7fffu + ((v.u >> 16) & 1u);
  return (unsigned short)(r >> 16);
}

// async global->LDS, 16B per lane; LDS dest is wave-uniform base + lane*16
__device__ __forceinline__ void gl_lds16(const unsigned short* g, unsigned short* l) {
  __builtin_amdgcn_global_load_lds((const __attribute__((address_space(1))) void*)g,
                                   (__attribute__((address_space(3))) void*)l, 16, 0, 0);
}

// ---------------- x fp32 -> bf16 ----------------
__global__ __launch_bounds__(256) void cast_x(const float* __restrict__ x,
                                              unsigned short* __restrict__ xb) {
  int i = (blockIdx.x * 256 + threadIdx.x) * 4;
  float4 v = *(const float4*)(x + i);
  ushort4 o;
  o.x = f2b(v.x); o.y = f2b(v.y); o.z = f2b(v.z); o.w = f2b(v.w);
  *(ushort4*)(xb + i) = o;
}

// ---------------- W -> W^T bf16 (4 weights) ----------------
__global__ __launch_bounds__(256) void trans_w(const float* __restrict__ Wq,
    const float* __restrict__ Wk, const float* __restrict__ Wv,
    const float* __restrict__ Wo, unsigned short* __restrict__ WT) {
  const int z = blockIdx.z;
  const float* W = (z == 0) ? Wq : (z == 1) ? Wk : (z == 2) ? Wv : Wo;
  unsigned short* T = WT + (size_t)z * DIM * INNER;
  __shared__ float tile[64][65];
  const int n0 = blockIdx.x * 64, k0 = blockIdx.y * 64;
  const int tid = threadIdx.x;
#pragma unroll
  for (int it = 0; it < 16; it++) {
    int lin = it * 256 + tid;
    int r = lin >> 6, c = lin & 63;
    tile[r][c] = W[(size_t)(k0 + r) * 1024 + n0 + c];
  }
  __syncthreads();
#pragma unroll
  for (int it = 0; it < 16; it++) {
    int lin = it * 256 + tid;
    int r = lin >> 6, c = lin & 63;
    T[(size_t)(n0 + r) * 1024 + k0 + c] = f2b(tile[c][r]);
  }
}

// ---------------- QKV projection GEMM (r10 structure + min-waves=3) --------
// r10 form (2 barriers/K-step, single 32KB LDS buffer set — the r11 dbuf
// regressed: 64KB LDS cut residency and gl_lds writes contended with
// compute ds_reads). Counter signature is latency-bound: MfmaUtil 26%,
// HBM 16%, ~2 blocks/CU (112 VGPR + 64 AGPR = 176 regs -> 2 waves/SIMD).
// __launch_bounds__(256,3) caps at 170 regs -> 3 blocks/CU (+50% TLP);
// only 6 regs over, recoverable without spill. Tripwires: WRITE_SIZE ~50MB
// (no scratch), absmax bit-identical.
__global__ __launch_bounds__(256, 3) void qkv_gemm(const unsigned short* __restrict__ xb,
    const unsigned short* __restrict__ WT, unsigned short* __restrict__ QKV) {
  __shared__ __align__(16) unsigned short As[2 * 128 * 32];
  __shared__ __align__(16) unsigned short Bs[2 * 128 * 32];
  const int tid = threadIdx.x;
  const int lane = tid & 63, wv = tid >> 6;
  const int quad = lane >> 4, l16 = lane & 15;
  const int wm = wv >> 1, wn = wv & 1;
  const int m0 = blockIdx.x * 128, n0 = blockIdx.y * 128;
  const unsigned short* Ag = xb + (size_t)m0 * DIM;
  const unsigned short* Bg = WT + (size_t)blockIdx.z * DIM * INNER + (size_t)n0 * DIM;
  unsigned short* Out = QKV + (size_t)blockIdx.z * M_TOK * INNER;

  f32x4 zero = {0.f, 0.f, 0.f, 0.f};
  f32x4 acc[4][4];
#pragma unroll
  for (int i = 0; i < 4; i++)
#pragma unroll
    for (int j = 0; j < 4; j++) acc[i][j] = zero;

  const int lr = lane >> 2, lc = (lane & 3) * 8;
  const int c0 = wv * 2, c1 = wv * 2 + 1;

  for (int k0 = 0; k0 < DIM; k0 += 64) {
    __syncthreads();
#pragma unroll
    for (int h = 0; h < 2; h++) {
      gl_lds16(&Ag[(size_t)(c0 * 16 + lr) * DIM + k0 + h * 32 + lc], &As[h * 4096 + c0 * 512]);
      gl_lds16(&Ag[(size_t)(c1 * 16 + lr) * DIM + k0 + h * 32 + lc], &As[h * 4096 + c1 * 512]);
      gl_lds16(&Bg[(size_t)(c0 * 16 + lr) * DIM + k0 + h * 32 + lc], &Bs[h * 4096 + c0 * 512]);
      gl_lds16(&Bg[(size_t)(c1 * 16 + lr) * DIM + k0 + h * 32 + lc], &Bs[h * 4096 + c1 * 512]);
    }
    __syncthreads();
#pragma unroll
    for (int h = 0; h < 2; h++) {
      bf16x8 af[4], bfr[4];
#pragma unroll
      for (int i = 0; i < 4; i++)
        af[i] = *(const bf16x8*)&As[h * 4096 + (wm * 64 + i * 16 + l16) * 32 + quad * 8];
#pragma unroll
      for (int j = 0; j < 4; j++)
        bfr[j] = *(const bf16x8*)&Bs[h * 4096 + (wn * 64 + j * 16 + l16) * 32 + quad * 8];
#pragma unroll
      for (int i = 0; i < 4; i++)
#pragma unroll
        for (int j = 0; j < 4; j++)
          acc[i][j] = __builtin_amdgcn_mfma_f32_16x16x32_bf16(af[i], bfr[j], acc[i][j], 0, 0, 0);
    }
  }
  if (blockIdx.z != 2) {
    const float cs = (blockIdx.z == 0) ? QSCALE : 1.0f;
#pragma unroll
    for (int i = 0; i < 4; i++) {
#pragma unroll
      for (int j = 0; j < 4; j++) {
        int n = n0 + wn * 64 + j * 16 + l16;
#pragma unroll
        for (int r = 0; r < 4; r++) {
          int m = m0 + wm * 64 + i * 16 + quad * 4 + r;
          Out[(size_t)m * INNER + n] = f2b(acc[i][j][r] * cs);
        }
      }
    }
  } else {
#pragma unroll
    for (int i = 0; i < 4; i++) {
#pragma unroll
      for (int j = 0; j < 4; j++) {
        int n = n0 + wn * 64 + j * 16 + l16;
        int h = n >> 6, dh = n & 63;
        int mbase = m0 + wm * 64 + i * 16 + quad * 4;
        int b = mbase >> 11, nq = mbase & 2047;
        unsigned lo = (unsigned)f2b(acc[i][j][0]) | ((unsigned)f2b(acc[i][j][1]) << 16);
        unsigned hi = (unsigned)f2b(acc[i][j][2]) | ((unsigned)f2b(acc[i][j][3]) << 16);
        uint2 pw; pw.x = lo; pw.y = hi;
        *(uint2*)&Out[((size_t)(b * H_N + h) * DH + dh) * N_SEQ + nq] = pw;
      }
    }
  }
}

// ---------------- flash attention (round-10 kernel, unchanged) -------------
#define KT 64
#define LSTR 72

__global__ __launch_bounds__(512, 4) void attn(const unsigned short* __restrict__ Q,
    const unsigned short* __restrict__ K, const unsigned short* __restrict__ VT,
    unsigned short* __restrict__ O) {
  __shared__ __align__(16) unsigned short Ks[2][KT * LSTR];
  __shared__ __align__(16) unsigned short VTs[2][DH * LSTR];
  const int tid = threadIdx.x;
  const int lane = tid & 63, w = tid >> 6;          // w in 0..7
  const int quad = lane >> 4, l16 = lane & 15;
  const int bh = blockIdx.y;
  const int b = bh >> 4, h = bh & 15;
  const int q0 = blockIdx.x * 256;                  // 256 q-rows per block
  const unsigned short* Qp = Q + ((size_t)b * N_SEQ) * INNER + h * DH;
  const unsigned short* Kp = K + ((size_t)b * N_SEQ) * INNER + h * DH;
  const unsigned short* VTp = VT + (size_t)bh * DH * N_SEQ;

  // Q fragments: this wave's 32 q-rows (2 x 16), B-operand layout
  bf16x8 aq[2][2];
#pragma unroll
  for (int qi = 0; qi < 2; qi++) {
    const unsigned short* qr = Qp + (size_t)(q0 + w * 32 + qi * 16 + l16) * INNER;
    aq[qi][0] = *(const bf16x8*)&qr[quad * 8];
    aq[qi][1] = *(const bf16x8*)&qr[32 + quad * 8];
  }

  bf16x8 vone;
#pragma unroll
  for (int j = 0; j < 8; j++) vone[j] = (short)0x3F80;

  f32x4 zero = {0.f, 0.f, 0.f, 0.f};
  f32x4 oacc[2][4];
  f32x4 lacc[2];
#pragma unroll
  for (int qi = 0; qi < 2; qi++) {
    lacc[qi] = zero;
#pragma unroll
    for (int t = 0; t < 4; t++) oacc[qi][t] = zero;
  }

  // staging lane map: 512 threads cover 64 rows x 64 shorts in one pass
  const int srow = tid >> 3, scol = (tid & 7) * 8;

  // prefetch tile 0 into registers
  uint4 kreg, vreg;
  kreg = *(const uint4*)&Kp[(size_t)srow * INNER + scol];
  vreg = *(const uint4*)&VTp[(size_t)srow * N_SEQ + scol];

  const int NT = N_SEQ / KT;
  for (int it = 0; it < NT; it++) {
    unsigned short* ks = Ks[it & 1];
    unsigned short* vs = VTs[it & 1];
    *(uint4*)&ks[srow * LSTR + scol] = kreg;
    *(uint4*)&vs[srow * LSTR + scol] = vreg;
    __syncthreads();   // stage writes drained; prior readers of this buffer done
    if (it + 1 < NT) {
      const int kn = (it + 1) * KT;
      kreg = *(const uint4*)&Kp[(size_t)(kn + srow) * INNER + scol];
      vreg = *(const uint4*)&VTp[(size_t)srow * N_SEQ + kn + scol];
    }

    // two key-halves of 32; per half: QK^T -> exp2 -> in-reg repack -> PV
#pragma unroll
    for (int half = 0; half < 2; half++) {
      f32x4 s[2][2];
#pragma unroll
      for (int t = 0; t < 2; t++)
#pragma unroll
        for (int qi = 0; qi < 2; qi++) s[t][qi] = zero;

#pragma unroll
      for (int kk = 0; kk < 2; kk++) {
#pragma unroll
        for (int t = 0; t < 2; t++) {
          bf16x8 ka = *(const bf16x8*)&ks[((half * 2 + t) * 16 + l16) * LSTR + kk * 32 + quad * 8];
#pragma unroll
          for (int qi = 0; qi < 2; qi++)
            s[t][qi] = __builtin_amdgcn_mfma_f32_16x16x32_bf16(ka, aq[qi][kk], s[t][qi], 0, 0, 0);
        }
      }

      bf16x8 pa[2];
#pragma unroll
      for (int qi = 0; qi < 2; qi++) {
#pragma unroll
        for (int t = 0; t < 2; t++)
#pragma unroll
          for (int r = 0; r < 4; r++)
            s[t][qi][r] = __builtin_amdgcn_exp2f(s[t][qi][r]);
        // C-layout (4 keys/lane) -> A-layout (8 keys/lane), in registers.
        // Fused asm with explicit s_nop wait-states: the CDNA VALU-write ->
        // v_permlane*-read hazard is NOT compiler-covered across asm borders
        // (this was the r2/r3/r5/r8 corruption; validated fix in r9).
        unsigned lo0, hi0, lo1, hi1;
        asm volatile(
            "v_cvt_pk_bf16_f32 %0, %4, %5\n\t"
            "v_cvt_pk_bf16_f32 %1, %6, %7\n\t"
            "v_cvt_pk_bf16_f32 %2, %8, %9\n\t"
            "v_cvt_pk_bf16_f32 %3, %10, %11\n\t"
            "s_nop 1\n\t"
            "v_permlane32_swap_b32 %0, %2\n\t"
            "v_permlane32_swap_b32 %1, %3\n\t"
            "s_nop 1\n\t"
            "v_permlane16_swap_b32 %0, %2\n\t"
            "v_permlane16_swap_b32 %1, %3\n\t"
            "s_nop 1"
            : "=&v"(lo0), "=&v"(hi0), "=&v"(lo1), "=&v"(hi1)
            : "v"(s[0][qi][0]), "v"(s[0][qi][1]), "v"(s[0][qi][2]), "v"(s[0][qi][3]),
              "v"(s[1][qi][0]), "v"(s[1][qi][1]), "v"(s[1][qi][2]), "v"(s[1][qi][3]));
        u32x4 pk;
        pk.x = lo0; pk.y = hi0; pk.z = lo1; pk.w = hi1;
        pa[qi] = __builtin_bit_cast(bf16x8, pk);
      }

      // PV + row-sum for this 32-key half
      lacc[0] = __builtin_amdgcn_mfma_f32_16x16x32_bf16(pa[0], vone, lacc[0], 0, 0, 0);
      lacc[1] = __builtin_amdgcn_mfma_f32_16x16x32_bf16(pa[1], vone, lacc[1], 0, 0, 0);
#pragma unroll
      for (int t2 = 0; t2 < 4; t2++) {
        bf16x8 vf = *(const bf16x8*)&vs[(t2 * 16 + l16) * LSTR + half * 32 + quad * 8];
        oacc[0][t2] = __builtin_amdgcn_mfma_f32_16x16x32_bf16(pa[0], vf, oacc[0][t2], 0, 0, 0);
        oacc[1][t2] = __builtin_amdgcn_mfma_f32_16x16x32_bf16(pa[1], vf, oacc[1][t2], 0, 0, 0);
      }
    }
  }

#pragma unroll
  for (int qi = 0; qi < 2; qi++) {
#pragma unroll
    for (int r = 0; r < 4; r++) {
      float rl = __builtin_amdgcn_rcpf(lacc[qi][r]);
      int qrow = q0 + w * 32 + qi * 16 + quad * 4 + r;
#pragma unroll
      for (int t2 = 0; t2 < 4; t2++) {
        int col = h * DH + t2 * 16 + l16;
        O[((size_t)b * N_SEQ + qrow) * INNER + col] = f2b(oacc[qi][t2][r] * rl);
      }
    }
  }
}

// ---------------- output GEMM (r10 form): 128x64 tile, BK=64 ---------------
__global__ __launch_bounds__(256) void out_gemm(const unsigned short* __restrict__ Ob,
    const unsigned short* __restrict__ WoT, const float* __restrict__ bo,
    float* __restrict__ out) {
  __shared__ __align__(16) unsigned short As[2 * 128 * 32];
  __shared__ __align__(16) unsigned short Bs[2 * 64 * 32];
  const int tid = threadIdx.x;
  const int lane = tid & 63, wv = tid >> 6;
  const int quad = lane >> 4, l16 = lane & 15;
  const int wm = wv >> 1, wn = wv & 1;
  const int m0 = blockIdx.x * 128, n0 = blockIdx.y * 64;
  const unsigned short* Ag = Ob + (size_t)m0 * INNER;
  const unsigned short* Bg = WoT + (size_t)n0 * INNER;

  f32x4 zero = {0.f, 0.f, 0.f, 0.f};
  f32x4 acc[4][2];
#pragma unroll
  for (int i = 0; i < 4; i++)
#pragma unroll
    for (int j = 0; j < 2; j++) acc[i][j] = zero;

  const int lr = lane >> 2, lc = (lane & 3) * 8;
  const int c0 = wv * 2, c1 = wv * 2 + 1;
  const int cb = wv;

  for (int k0 = 0; k0 < INNER; k0 += 64) {
    __syncthreads();
#pragma unroll
    for (int h = 0; h < 2; h++) {
      gl_lds16(&Ag[(size_t)(c0 * 16 + lr) * INNER + k0 + h * 32 + lc], &As[h * 4096 + c0 * 512]);
      gl_lds16(&Ag[(size_t)(c1 * 16 + lr) * INNER + k0 + h * 32 + lc], &As[h * 4096 + c1 * 512]);
      gl_lds16(&Bg[(size_t)(cb * 16 + lr) * INNER + k0 + h * 32 + lc], &Bs[h * 2048 + cb * 512]);
    }
    __syncthreads();
#pragma unroll
    for (int h = 0; h < 2; h++) {
      bf16x8 af[4], bfr[2];
#pragma unroll
      for (int i = 0; i < 4; i++)
        af[i] = *(const bf16x8*)&As[h * 4096 + (wm * 64 + i * 16 + l16) * 32 + quad * 8];
#pragma unroll
      for (int j = 0; j < 2; j++)
        bfr[j] = *(const bf16x8*)&Bs[h * 2048 + (wn * 32 + j * 16 + l16) * 32 + quad * 8];
#pragma unroll
      for (int i = 0; i < 4; i++)
#pragma unroll
        for (int j = 0; j < 2; j++)
          acc[i][j] = __builtin_amdgcn_mfma_f32_16x16x32_bf16(af[i], bfr[j], acc[i][j], 0, 0, 0);
    }
  }
#pragma unroll
  for (int i = 0; i < 4; i++) {
#pragma unroll
    for (int j = 0; j < 2; j++) {
      int n = n0 + wn * 32 + j * 16 + l16;
      float bias = bo[n];
#pragma unroll
      for (int r = 0; r < 4; r++) {
        int m = m0 + wm * 64 + i * 16 + quad * 4 + r;
        out[(size_t)m * DIM + n] = acc[i][j][r] + bias;
      }
    }
  }
}

extern "C" void kernel_launch(void* const* d_in, const int* in_sizes, int n_in,
                              void* d_out, int out_size, void* d_ws, size_t ws_size,
                              hipStream_t stream) {
  const float* x  = (const float*)d_in[0];
  const float* Wq = (const float*)d_in[1];
  const float* Wk = (const float*)d_in[2];
  const float* Wv = (const float*)d_in[3];
  const float* Wo = (const float*)d_in[4];
  const float* bo = (const float*)d_in[5];

  char* ws = (char*)d_ws;
  unsigned short* xb   = (unsigned short*)ws;                       // 16 MiB
  unsigned short* WT   = (unsigned short*)(ws + (size_t)16777216);  // 8 MiB
  unsigned short* QKV  = (unsigned short*)(ws + (size_t)25165824);  // 48 MiB: Q,K tok-major + V^T
  unsigned short* Obuf = (unsigned short*)(ws + (size_t)75497472);  // 16 MiB

  cast_x<<<dim3(8192), 256, 0, stream>>>(x, xb);
  trans_w<<<dim3(16, 16, 4), 256, 0, stream>>>(Wq, Wk, Wv, Wo, WT);
  qkv_gemm<<<dim3(64, 8, 3), 256, 0, stream>>>(xb, WT, QKV);
  attn<<<dim3(8, 64), 512, 0, stream>>>(QKV,
                                        QKV + (size_t)M_TOK * INNER,
                                        QKV + (size_t)2 * M_TOK * INNER,
                                        Obuf);
  out_gemm<<<dim3(64, 16), 256, 0, stream>>>(Obuf, WT + (size_t)3 * DIM * INNER, bo,
                                             (float*)d_out);
}